// Round 7
// baseline (352.698 us; speedup 1.0000x reference)
//
#include <hip/hip_runtime.h>
#include <hip/hip_bf16.h>
#include <math.h>

// ---------------- problem constants ----------------
#define BB 262144
#define NST 20
#define RHc 0.006f            // R*H
#define BHc 0.01f             // B_DRIFT*H
#define SIGc 0.2f
#define CURTc 0.005f
#define DISCf 0.8869204367171575f   // exp(-0.12)

// ---------------- launch geometry ----------------
#define THB 256
#define NBLK_SIM 2048          // 32 paths per wave, 128 per block
#define H1_BLK 16
#define H1_THR 1024
#define W_BLK 256
#define W_THR 256

// ---------------- workspace layout (floats from ws base unless noted) ----------------
#define SIMP_OFF  BB                          // float[NBLK_SIM*5]
#define TAILP_OFF (SIMP_OFF + NBLK_SIM * 5)   // float[W_BLK*4]
#define ICTRL     (TAILP_OFF + W_BLK * 4)     // int region base (= BB+11264)
// ctrl ints:
#define H2_OFF 0                      // 4*2048
#define H3_OFF 8192                   // 4*1024
#define CNT_OFF 12288
#define ST_OFF  12296
#define SF_OFF  12320
#define ZTOT    12289
#define H1R_OFF 12352                 // 16 rows x 2048 ints (written AFTER sim)
// prep region OVERLAYS H1R (prep consumed by sim; H1R written by hist1 post-sim)
// max ws extent = ICTRL + 12352 + 32768 = 318,528 floats (< R4-proven 342,336)
#define PREP_OFF (ICTRL + H1R_OFF)
#define PSTR 1152                     // per-step: A2 512i | A3 512i | L1 48f | b2m 32f | b3m 32f
#define HEADO (19 * PSTR)             // Wu0m[8], bu0m[8]

// ---------------- types / helpers ----------------
typedef float f32x16 __attribute__((ext_vector_type(16)));
typedef short bf16x8 __attribute__((ext_vector_type(8)));
union F8  { int4 i; bf16x8 b; };
union BFR { int u[4]; bf16x8 b; };
union C16 { float4 f4[4]; f32x16 v; };

__device__ __forceinline__ unsigned pkbf(float lo, float hi) {
    __hip_bfloat162 t = __float22bfloat162_rn(make_float2(lo, hi));  // x=lo(low16), y=hi(high16)
    unsigned r;
    __builtin_memcpy(&r, &t, 4);
    return r;
}
__device__ __forceinline__ unsigned fkey(float f) {
    unsigned u = __float_as_uint(f);
    return (u & 0x80000000u) ? ~u : (u | 0x80000000u);
}
__device__ __forceinline__ float funkey(unsigned k) {
    return __uint_as_float((k & 0x80000000u) ? (k ^ 0x80000000u) : ~k);
}
__device__ __forceinline__ float wred(float v) {
#pragma unroll
    for (int o = 32; o > 0; o >>= 1) v += __shfl_down(v, o);
    return v;
}
__device__ __forceinline__ unsigned short f2bf(float f) {   // RNE
    unsigned u = __float_as_uint(f);
    unsigned r = u + 0x7fffu + ((u >> 16) & 1u);
    return (unsigned short)(r >> 16);
}

__global__ void zero_kernel(int* __restrict__ ctrl) {
    int i = blockIdx.x * blockDim.x + threadIdx.x;
    if (i < ZTOT) ctrl[i] = 0;
}

// ---------------- prep: swizzle weights into MFMA fragment order ----------------
// k-slot labeling (32x32x16 bf16): lane l, dword v, half h:
//   k = 8*(v>>1) + 4*(l>>5) + 2*(v&1) + h ; A row / B col = l&31
// (consistent bijection used for BOTH A and B fragments -> cancels vs HW order)
__global__ void prep_kernel(const float* __restrict__ Wu0, const float* __restrict__ bu0,
                            const float* __restrict__ W1, const float* __restrict__ b1,
                            const float* __restrict__ W2, const float* __restrict__ b2,
                            const float* __restrict__ W3, const float* __restrict__ b3,
                            float* __restrict__ prepF)
{
    const int s = blockIdx.x, tid = threadIdx.x;
    int* prepI = (int*)prepF;
    if (s < 19) {
        for (int t = tid; t < 512; t += 256) {
            int c = t >> 8, l = (t >> 2) & 63, v = t & 3;
            int g = l >> 5, row = l & 31;
            int kb = 16 * c + 8 * (v >> 1) + 4 * g + 2 * (v & 1);
            // A2 = W2^T : A[m=j][k=i] = W2[s][i][j]
            float lo = (row < 20 && kb     < 20) ? W2[s * 400 + kb * 20 + row]       : 0.f;
            float hi = (row < 20 && kb + 1 < 20) ? W2[s * 400 + (kb + 1) * 20 + row] : 0.f;
            prepI[s * PSTR + c * 256 + l * 4 + v] = (int)(((unsigned)f2bf(hi) << 16) | f2bf(lo));
            // A3 = W3^T : A[m=d][k=j] = W3[s][j][d]
            float lo3 = (row < 5 && kb     < 20) ? W3[s * 100 + kb * 5 + row]       : 0.f;
            float hi3 = (row < 5 && kb + 1 < 20) ? W3[s * 100 + (kb + 1) * 5 + row] : 0.f;
            prepI[s * PSTR + 512 + c * 256 + l * 4 + v] = (int)(((unsigned)f2bf(hi3) << 16) | f2bf(lo3));
        }
        if (tid < 48) {   // layer-1 weights/biases in B-fragment k-slot order, per g
            int g = tid / 24, j0 = tid % 24, j = j0 % 12;
            int n = (j < 4) ? 4 * g + j : (j < 8) ? 8 + 4 * g + (j - 4) : 16 + 4 * g + (j - 8);
            float val = 0.f;
            if (n < 20) val = (j0 >= 12) ? b1[s * 20 + n] : W1[s * 20 + n];
            prepF[s * PSTR + 1024 + g * 24 + j0] = val;
        }
        if (tid < 32) {   // biases mapped into C-layout rows
            int g = tid >> 4, r = tid & 15;
            int row = (r & 3) + 8 * (r >> 2) + 4 * g;
            prepF[s * PSTR + 1072 + tid] = (row < 20) ? b2[s * 20 + row] : 0.f;
            prepF[s * PSTR + 1104 + tid] = (row < 5)  ? b3[s * 5 + row]  : 0.f;
        }
    } else {
        if (tid < 8) {    // Wu0/bu0 mapped to alpha C-regs 0-3 per g (d = r + 4g)
            int g = tid >> 2, r = tid & 3, d = r + 4 * g;
            prepF[HEADO + tid]     = (d < 5) ? Wu0[d] : 0.f;
            prepF[HEADO + 8 + tid] = (d < 5) ? bu0[d] : 0.f;
        }
    }
}

// ---------------- sim: MFMA MLP, 32 paths/wave ----------------
__global__ __launch_bounds__(THB, 2) void sim_kernel(
    const float* __restrict__ x_in, const float* __restrict__ dW,
    const float* __restrict__ Wo, const float* __restrict__ bo,
    const float* __restrict__ Wk, const float* __restrict__ bk,
    float* __restrict__ ws, int* __restrict__ ctrl, float* __restrict__ out,
    const float* __restrict__ prepF)
{
    __shared__ float red[4][5];
    __shared__ int lastF;
    const int tid = threadIdx.x;
    const int l = tid & 63;
    const int g = l >> 5;
    const bool gm = (g == 0);
    const int p = blockIdx.x * 128 + (tid >> 6) * 32 + (l & 31);

    float x = x_in[p];

    // softmax head (per path; uniform weight reads)
    float z[11], zm = -1e30f;
#pragma unroll
    for (int j = 0; j < 11; j++) {
        z[j] = fmaf(x, Wo[j], bo[j]);
        zm = fmaxf(zm, z[j]);
    }
    float se = 0.f;
#pragma unroll
    for (int j = 0; j < 11; j++) se += __expf(z[j] - zm);
    float smv = __expf(z[10] - zm) / se;

    float K0 = 1.f + 0.25f * tanhf(fmaf(x, Wk[0], bk[0]));

    // alpha in layer-3 C-layout: reg r -> asset r+4g (g1 r>0 -> exact 0)
    float a[4];
    {
        float4 w4 = *(const float4*)(prepF + HEADO + g * 4);
        float4 b4 = *(const float4*)(prepF + HEADO + 8 + g * 4);
        a[0] = fmaf(x, w4.x, b4.x); a[1] = fmaf(x, w4.y, b4.y);
        a[2] = fmaf(x, w4.z, b4.z); a[3] = fmaf(x, w4.w, b4.w);
    }
    float S[4] = {1.f, 1.f, 1.f, 1.f}, Nm1[4], dwb[4];
    float SQ0 = 1.f, dNs = 0.f;
#pragma unroll
    for (int e = 0; e < 4; e++) Nm1[e] = a[e];

    {   // dW lane slots: g0 -> d0..3, g1 -> d4,0,0,0 (scalar dword loads)
        const float* pw = dW + (size_t)p * 5;
        float d0 = pw[0], d1 = pw[1], d2v = pw[2], d3v = pw[3], d4 = pw[4];
        dwb[0] = gm ? d0 : d4;
        dwb[1] = gm ? d1 : 0.f; dwb[2] = gm ? d2v : 0.f; dwb[3] = gm ? d3v : 0.f;
    }

#pragma unroll 1
    for (int n = 1; n <= NST; n++) {
        float dwc[4];
#pragma unroll
        for (int e = 0; e < 4; e++) dwc[e] = dwb[e];
        if (n < NST) {   // prefetch next step's noise
            const float* pw = dW + ((size_t)n * BB + p) * 5;
            float d0 = pw[0], d1 = pw[1], d2v = pw[2], d3v = pw[3], d4 = pw[4];
            dwb[0] = gm ? d0 : d4;
            dwb[1] = gm ? d1 : 0.f; dwb[2] = gm ? d2v : 0.f; dwb[3] = gm ? d3v : 0.f;
        }
        // Euler step (per-lane 4 asset slots; g1 extra slots are exact zeros)
        float du = 0.f, us = 0.f;
#pragma unroll
        for (int e = 0; e < 4; e++) {
            float f = fmaf(SIGc, dwc[e], BHc);
            du = fmaf(a[e], f, du);
            us += a[e];
            float Np = a[e] * __builtin_amdgcn_rcpf(S[e]);
            dNs += fabsf(Np - Nm1[e]);
            Nm1[e] = Np;
            S[e] = fmaf(S[e], f, S[e]);          // S *= 1 + BH + SIG*dw
        }
        SQ0 = fmaf(SQ0, fmaf(SIGc, dwc[0], RHc), SQ0);
        du += __shfl_xor(du, 32);
        us += __shfl_xor(us, 32);
        x = fmaf(x - us, RHc, x) + du;

        if (n < NST) {
            const float* sb = prepF + (n - 1) * PSTR;
            // ---- layer 1: h1 directly in B-fragment k-slot order ----
            const float4* lw = (const float4*)(sb + 1024 + g * 24);
            float4 wA = lw[0], wB = lw[1], wC = lw[2];
            float4 bA = lw[3], bB = lw[4], bC = lw[5];
            float h[12];
            h[0]  = fmaxf(fmaf(x, wA.x, bA.x), 0.f); h[1]  = fmaxf(fmaf(x, wA.y, bA.y), 0.f);
            h[2]  = fmaxf(fmaf(x, wA.z, bA.z), 0.f); h[3]  = fmaxf(fmaf(x, wA.w, bA.w), 0.f);
            h[4]  = fmaxf(fmaf(x, wB.x, bB.x), 0.f); h[5]  = fmaxf(fmaf(x, wB.y, bB.y), 0.f);
            h[6]  = fmaxf(fmaf(x, wB.z, bB.z), 0.f); h[7]  = fmaxf(fmaf(x, wB.w, bB.w), 0.f);
            h[8]  = fmaxf(fmaf(x, wC.x, bC.x), 0.f); h[9]  = fmaxf(fmaf(x, wC.y, bC.y), 0.f);
            h[10] = fmaxf(fmaf(x, wC.z, bC.z), 0.f); h[11] = fmaxf(fmaf(x, wC.w, bC.w), 0.f);
            BFR b1c0, b1c1;
            b1c0.u[0] = pkbf(h[0], h[1]);  b1c0.u[1] = pkbf(h[2], h[3]);
            b1c0.u[2] = pkbf(h[4], h[5]);  b1c0.u[3] = pkbf(h[6], h[7]);
            b1c1.u[0] = pkbf(h[8], h[9]);  b1c1.u[1] = pkbf(h[10], h[11]);
            b1c1.u[2] = 0;                 b1c1.u[3] = 0;
            // ---- layer 2: D2 = W2^T * h1 + b2 ----
            F8 A2c0, A2c1;
            const int4* a2p = (const int4*)sb + l;
            A2c0.i = a2p[0]; A2c1.i = a2p[64];
            C16 c2;
            {
                const float4* bp = (const float4*)(sb + 1072 + g * 16);
                c2.f4[0] = bp[0]; c2.f4[1] = bp[1]; c2.f4[2] = bp[2]; c2.f4[3] = bp[3];
            }
            f32x16 d2 = __builtin_amdgcn_mfma_f32_32x32x16_bf16(A2c0.b, b1c0.b, c2.v, 0, 0, 0);
            d2 = __builtin_amdgcn_mfma_f32_32x32x16_bf16(A2c1.b, b1c1.b, d2, 0, 0, 0);
            // relu on real rows (regs 12-15 are exact zeros)
            float h2r[12];
#pragma unroll
            for (int i = 0; i < 12; i++) h2r[i] = fmaxf(d2[i], 0.f);
            // ---- repack h2 C-layout -> layer-3 B-fragments (no cross-lane) ----
            BFR b2c0, b2c1;
            b2c0.u[0] = pkbf(h2r[0], h2r[1]); b2c0.u[1] = pkbf(h2r[2], h2r[3]);
            b2c0.u[2] = pkbf(h2r[4], h2r[5]); b2c0.u[3] = pkbf(h2r[6], h2r[7]);
            b2c1.u[0] = pkbf(h2r[8], h2r[9]); b2c1.u[1] = pkbf(h2r[10], h2r[11]);
            b2c1.u[2] = 0;                    b2c1.u[3] = 0;
            // ---- layer 3: D3 = W3^T * h2 + b3 ----
            F8 A3c0, A3c1;
            const int4* a3p = (const int4*)(sb + 512) + l;
            A3c0.i = a3p[0]; A3c1.i = a3p[64];
            C16 c3;
            {
                const float4* bp = (const float4*)(sb + 1104 + g * 16);
                c3.f4[0] = bp[0]; c3.f4[1] = bp[1]; c3.f4[2] = bp[2]; c3.f4[3] = bp[3];
            }
            f32x16 d3 = __builtin_amdgcn_mfma_f32_32x32x16_bf16(A3c0.b, b2c0.b, c3.v, 0, 0, 0);
            d3 = __builtin_amdgcn_mfma_f32_32x32x16_bf16(A3c1.b, b2c1.b, d3, 0, 0, 0);
            a[0] = d3[0]; a[1] = d3[1]; a[2] = d3[2]; a[3] = d3[3];
        }
    }

    // epilogue
    float dnO = __shfl_xor(dNs, 32);
    float xx = fmaf(-CURTc, dNs + dnO, x);
    if (gm) ws[p] = xx;
    float v0 = gm ? xx : 0.f;
    float v1 = gm ? xx * xx : 0.f;
    float v2 = gm ? fmaxf(S[0] - K0, 0.f) : 0.f;
    float v3 = gm ? fmaxf(SQ0 - K0, 0.f) : 0.f;
    float v4 = gm ? smv : 0.f;

    v0 = wred(v0); v1 = wred(v1); v2 = wred(v2); v3 = wred(v3); v4 = wred(v4);
    int wid = tid >> 6, lane = tid & 63;
    if (lane == 0) { red[wid][0] = v0; red[wid][1] = v1; red[wid][2] = v2; red[wid][3] = v3; red[wid][4] = v4; }
    __syncthreads();
    if (tid == 0) {
        float s0 = 0, s1 = 0, s2 = 0, s3 = 0, s4 = 0;
#pragma unroll
        for (int w = 0; w < 4; w++) { s0 += red[w][0]; s1 += red[w][1]; s2 += red[w][2]; s3 += red[w][3]; s4 += red[w][4]; }
        float* part = ws + SIMP_OFF + blockIdx.x * 5;
        part[0] = s0; part[1] = s1; part[2] = s2; part[3] = s3; part[4] = s4;
    }
    __threadfence();
    if (tid == 0) lastF = (atomicAdd(&ctrl[CNT_OFF], 1) == NBLK_SIM - 1);
    __syncthreads();
    if (!lastF) return;
    __threadfence();

    const float* part = ws + SIMP_OFF;
    float a0 = 0, a1 = 0, a2 = 0, a3 = 0, a4 = 0;
    for (int r = tid; r < NBLK_SIM; r += THB) {
        const float* pr = part + r * 5;
        a0 += pr[0]; a1 += pr[1]; a2 += pr[2]; a3 += pr[3]; a4 += pr[4];
    }
    a0 = wred(a0); a1 = wred(a1); a2 = wred(a2); a3 = wred(a3); a4 = wred(a4);
    if (lane == 0) { red[wid][0] = a0; red[wid][1] = a1; red[wid][2] = a2; red[wid][3] = a3; red[wid][4] = a4; }
    __syncthreads();
    if (tid == 0) {
        float Sx = 0, Sx2 = 0, SP = 0, SQs = 0, Ssm = 0;
#pragma unroll
        for (int w = 0; w < 4; w++) { Sx += red[w][0]; Sx2 += red[w][1]; SP += red[w][2]; SQs += red[w][3]; Ssm += red[w][4]; }
        float invB = 1.f / (float)BB;
        float meanx = Sx * invB;
        out[0] = -meanx;
        out[1] = Sx2 * invB - meanx * meanx;
        out[4] = (SP * invB) / (DISCf * (SQs * invB) + 1e-8f);
        out[5] = 1.f + 0.25f * tanhf(fmaf(x_in[0], Wk[1], bk[1]));
        out[6] = Ssm * invB;
    }
}

// ---------------- select helpers ----------------
__device__ __forceinline__ void aggAdd(int* h, int code) {
    bool act = (code >= 0);
    unsigned long long mask = __ballot(act);
    while (mask) {
        int leader = __ffsll((unsigned long long)mask) - 1;
        int lc = __shfl(code, leader);
        unsigned long long mm = __ballot(act && code == lc);
        if ((threadIdx.x & 63) == leader) atomicAdd(&h[lc], (int)__popcll(mm));
        mask &= ~mm;
    }
}

__device__ int excl_scan1024(int v, int tid, int* wsum) {
    __syncthreads();
    int lane = tid & 63, wid = tid >> 6;
    int inc = v;
#pragma unroll
    for (int o = 1; o < 64; o <<= 1) { int u = __shfl_up(inc, o); if (lane >= o) inc += u; }
    if (lane == 63) wsum[wid] = inc;
    __syncthreads();
    if (tid < 16) {
        int wv = wsum[tid], winc = wv;
#pragma unroll
        for (int o = 1; o < 16; o <<= 1) { int u = __shfl_up(winc, o); if (tid >= o) winc += u; }
        wsum[tid] = winc - wv;
    }
    __syncthreads();
    return wsum[wid] + inc - v;
}

__global__ __launch_bounds__(H1_THR) void hist1_kernel(const float* __restrict__ xf,
                                                       int* __restrict__ ctrl)
{
    __shared__ int lh[2048];
    const int tid = threadIdx.x, bl = blockIdx.x;
    for (int i = tid; i < 2048; i += H1_THR) lh[i] = 0;
    __syncthreads();
    const float4* xf4 = (const float4*)xf;
#pragma unroll
    for (int w = 0; w < 4; w++) {
        float4 v = xf4[(size_t)bl * 4096 + w * 1024 + tid];
        aggAdd(lh, (int)(fkey(v.x) >> 21));
        aggAdd(lh, (int)(fkey(v.y) >> 21));
        aggAdd(lh, (int)(fkey(v.z) >> 21));
        aggAdd(lh, (int)(fkey(v.w) >> 21));
    }
    __syncthreads();
    int* row = ctrl + H1R_OFF + bl * 2048;
    for (int i = tid; i < 2048; i += H1_THR) row[i] = lh[i];
}

__global__ __launch_bounds__(1024) void scan1_kernel(int* __restrict__ ctrl)
{
    __shared__ int wsum[16];
    __shared__ int binT[4], remT[4];
    const int tid = threadIdx.x;
    const int* rows = ctrl + H1R_OFF;
    int c0 = 0, c1 = 0;
    for (int r = 0; r < H1_BLK; r++) {
        c0 += rows[r * 2048 + 2 * tid];
        c1 += rows[r * 2048 + 2 * tid + 1];
    }
    int s = c0 + c1;
    int E = excl_scan1024(s, tid, wsum);
    const int RK[4] = {13107, 13108, 249035, 249036};
#pragma unroll
    for (int t = 0; t < 4; t++) {
        int r = RK[t];
        if (r >= E && r < E + s) {
            if (r < E + c0) { binT[t] = 2 * tid;     remT[t] = r - E; }
            else            { binT[t] = 2 * tid + 1; remT[t] = r - E - c0; }
        }
    }
    __syncthreads();
    if (tid == 0) {
        for (int t = 0; t < 4; t++) { ctrl[ST_OFF + t] = binT[t]; ctrl[ST_OFF + 4 + t] = remT[t]; }
        for (int t = 0; t < 4; t++) {
            int g = t;
            for (int q = 0; q < t; q++) if (binT[q] == binT[t]) { g = q; break; }
            ctrl[ST_OFF + 8 + t] = g;
        }
    }
}

__global__ __launch_bounds__(W_THR) void hist2_kernel(const float* __restrict__ xf,
                                                      int* __restrict__ ctrl)
{
    const int tid = threadIdx.x, bl = blockIdx.x;
    int pf[4], gp[4];
#pragma unroll
    for (int t = 0; t < 4; t++) { pf[t] = ctrl[ST_OFF + t]; gp[t] = ctrl[ST_OFF + 8 + t]; }
    float4 v = ((const float4*)xf)[(size_t)bl * W_THR + tid];
    float xv[4] = {v.x, v.y, v.z, v.w};
#pragma unroll
    for (int k = 0; k < 4; k++) {
        unsigned u = fkey(xv[k]);
        unsigned hi = u >> 21;
        int bin = (int)((u >> 10) & 2047u);
        int code = -1;
#pragma unroll
        for (int t = 0; t < 4; t++)
            if (gp[t] == t && (unsigned)pf[t] == hi) code = t * 2048 + bin;
        aggAdd(ctrl + H2_OFF, code);
    }
}

__global__ __launch_bounds__(1024) void scan2_kernel(int* __restrict__ ctrl)
{
    __shared__ int wsum[16];
    __shared__ int binT[4], remT[4];
    const int tid = threadIdx.x;
    for (int t = 0; t < 4; t++) {
        int g = ctrl[ST_OFF + 8 + t], rank = ctrl[ST_OFF + 4 + t];
        const int* h = ctrl + H2_OFF + g * 2048;
        int c0 = h[2 * tid], c1 = h[2 * tid + 1];
        int s = c0 + c1;
        int E = excl_scan1024(s, tid, wsum);
        if (rank >= E && rank < E + s) {
            if (rank < E + c0) { binT[t] = 2 * tid;     remT[t] = rank - E; }
            else               { binT[t] = 2 * tid + 1; remT[t] = rank - E - c0; }
        }
        __syncthreads();
    }
    if (tid == 0) {
        int P2n[4];
        for (int t = 0; t < 4; t++) {
            P2n[t] = (ctrl[ST_OFF + t] << 11) | binT[t];
            ctrl[ST_OFF + 12 + t] = P2n[t];
            ctrl[ST_OFF + 16 + t] = remT[t];
        }
        for (int t = 0; t < 4; t++) {
            int g = t;
            for (int q = 0; q < t; q++) if (P2n[q] == P2n[t]) { g = q; break; }
            ctrl[ST_OFF + 20 + t] = g;
        }
    }
}

__global__ __launch_bounds__(W_THR) void hist3_kernel(const float* __restrict__ xf,
                                                      int* __restrict__ ctrl)
{
    const int tid = threadIdx.x, bl = blockIdx.x;
    int pf[4], gp[4];
#pragma unroll
    for (int t = 0; t < 4; t++) { pf[t] = ctrl[ST_OFF + 12 + t]; gp[t] = ctrl[ST_OFF + 20 + t]; }
    float4 v = ((const float4*)xf)[(size_t)bl * W_THR + tid];
    float xv[4] = {v.x, v.y, v.z, v.w};
#pragma unroll
    for (int k = 0; k < 4; k++) {
        unsigned u = fkey(xv[k]);
        unsigned hi = u >> 10;
        int bin = (int)(u & 1023u);
        int code = -1;
#pragma unroll
        for (int t = 0; t < 4; t++)
            if (gp[t] == t && (unsigned)pf[t] == hi) code = t * 1024 + bin;
        aggAdd(ctrl + H3_OFF, code);
    }
}

__global__ __launch_bounds__(1024) void scan3_kernel(int* __restrict__ ctrl)
{
    __shared__ int wsum[16];
    __shared__ int binT[4];
    const int tid = threadIdx.x;
    for (int t = 0; t < 4; t++) {
        int g = ctrl[ST_OFF + 20 + t], rank = ctrl[ST_OFF + 16 + t];
        const int* h = ctrl + H3_OFF + g * 1024;
        int s = h[tid];
        int E = excl_scan1024(s, tid, wsum);
        if (rank >= E && rank < E + s) binT[t] = tid;
        __syncthreads();
    }
    if (tid == 0) {
        float* sf = (float*)(ctrl + SF_OFF);
        float v[4];
        for (int t = 0; t < 4; t++) {
            unsigned key = ((unsigned)ctrl[ST_OFF + 12 + t] << 10) | (unsigned)binT[t];
            v[t] = funkey(key);
            sf[t] = v[t];
        }
        sf[4] = v[0] + 0.15f * (v[1] - v[0]);  // p5  (idx 0.05*(B-1)=13107.15)
        sf[5] = v[2] + 0.85f * (v[3] - v[2]);  // p95 (idx 0.95*(B-1)=249035.85)
    }
}

__global__ __launch_bounds__(W_THR) void tail_kernel(const float* __restrict__ xf,
                                                     const int* __restrict__ ctrl,
                                                     float* __restrict__ ws)
{
    __shared__ float frd[4][4];
    const int tid = threadIdx.x, bl = blockIdx.x;
    const float* sf = (const float*)(ctrl + SF_OFF);
    const float p5 = sf[4], p95 = sf[5];
    float4 v = ((const float4*)xf)[(size_t)bl * W_THR + tid];
    float xv[4] = {v.x, v.y, v.z, v.w};
    float slo = 0.f, clo = 0.f, shi = 0.f, chi = 0.f;
#pragma unroll
    for (int k = 0; k < 4; k++) {
        float x = xv[k];
        if (x < p5)  { slo += x; clo += 1.f; }
        if (x > p95) { shi += x; chi += 1.f; }
    }
    slo = wred(slo); clo = wred(clo); shi = wred(shi); chi = wred(chi);
    int wid = tid >> 6, lane = tid & 63;
    if (lane == 0) { frd[wid][0] = slo; frd[wid][1] = clo; frd[wid][2] = shi; frd[wid][3] = chi; }
    __syncthreads();
    if (tid == 0) {
        float s0 = 0, s1 = 0, s2 = 0, s3 = 0;
#pragma unroll
        for (int w = 0; w < 4; w++) { s0 += frd[w][0]; s1 += frd[w][1]; s2 += frd[w][2]; s3 += frd[w][3]; }
        float* tp = ws + TAILP_OFF + bl * 4;
        tp[0] = s0; tp[1] = s1; tp[2] = s2; tp[3] = s3;
    }
}

__global__ __launch_bounds__(256) void tailfin_kernel(const float* __restrict__ ws,
                                                      float* __restrict__ out)
{
    __shared__ float frd[4][4];
    const int tid = threadIdx.x;
    const float* tp = ws + TAILP_OFF;
    float a0 = tp[tid * 4 + 0], a1 = tp[tid * 4 + 1], a2 = tp[tid * 4 + 2], a3 = tp[tid * 4 + 3];
    a0 = wred(a0); a1 = wred(a1); a2 = wred(a2); a3 = wred(a3);
    int wid = tid >> 6, lane = tid & 63;
    if (lane == 0) { frd[wid][0] = a0; frd[wid][1] = a1; frd[wid][2] = a2; frd[wid][3] = a3; }
    __syncthreads();
    if (tid == 0) {
        float Slo = 0, Clo = 0, Shi = 0, Chi = 0;
#pragma unroll
        for (int w = 0; w < 4; w++) { Slo += frd[w][0]; Clo += frd[w][1]; Shi += frd[w][2]; Chi += frd[w][3]; }
        out[2] = -Slo / fmaxf(Clo, 1.f);
        out[3] = -Shi / fmaxf(Chi, 1.f);
    }
}

// ---------------- host ----------------
extern "C" void kernel_launch(void* const* d_in, const int* in_sizes, int n_in,
                              void* d_out, int out_size, void* d_ws, size_t ws_size,
                              hipStream_t stream)
{
    const float* x_in = (const float*)d_in[0];
    const float* dW   = (const float*)d_in[1];
    const float* Wo   = (const float*)d_in[2];
    const float* bo   = (const float*)d_in[3];
    const float* Wk   = (const float*)d_in[4];
    const float* bk   = (const float*)d_in[5];
    const float* Wu0  = (const float*)d_in[6];
    const float* bu0  = (const float*)d_in[7];
    const float* W1   = (const float*)d_in[8];
    const float* b1   = (const float*)d_in[9];
    const float* W2   = (const float*)d_in[10];
    const float* b2   = (const float*)d_in[11];
    const float* W3   = (const float*)d_in[12];
    const float* b3   = (const float*)d_in[13];
    float* ws   = (float*)d_ws;
    int* ctrl   = (int*)d_ws + ICTRL;
    float* prep = ws + PREP_OFF;
    float* out  = (float*)d_out;

    zero_kernel<<<(ZTOT + 1023) / 1024, 1024, 0, stream>>>(ctrl);
    prep_kernel<<<20, 256, 0, stream>>>(Wu0, bu0, W1, b1, W2, b2, W3, b3, prep);
    sim_kernel<<<NBLK_SIM, THB, 0, stream>>>(x_in, dW, Wo, bo, Wk, bk, ws, ctrl, out, prep);
    hist1_kernel<<<H1_BLK, H1_THR, 0, stream>>>(ws, ctrl);
    scan1_kernel<<<1, 1024, 0, stream>>>(ctrl);
    hist2_kernel<<<W_BLK, W_THR, 0, stream>>>(ws, ctrl);
    scan2_kernel<<<1, 1024, 0, stream>>>(ctrl);
    hist3_kernel<<<W_BLK, W_THR, 0, stream>>>(ws, ctrl);
    scan3_kernel<<<1, 1024, 0, stream>>>(ctrl);
    tail_kernel<<<W_BLK, W_THR, 0, stream>>>(ws, ctrl, ws);
    tailfin_kernel<<<1, 256, 0, stream>>>(ws, out);
}

// Round 8
// 341.726 us; speedup vs baseline: 1.0321x; 1.0321x over previous
//
#include <hip/hip_runtime.h>
#include <hip/hip_bf16.h>
#include <math.h>

// ---------------- problem constants ----------------
#define BB 262144
#define NST 20
#define RHc 0.006f            // R*H
#define BHc 0.01f             // B_DRIFT*H
#define SIGc 0.2f
#define CURTc 0.005f
#define DISCf 0.8869204367171575f   // exp(-0.12)

// ---------------- launch geometry ----------------
#define THB 256
#define NBLK_SIM 2048          // 32 paths per wave, 128 per block
#define H1_BLK 16
#define H1_THR 1024
#define W_BLK 256
#define W_THR 256

// ---------------- workspace layout (floats from ws base unless noted) ----------------
#define SIMP_OFF  BB                          // float[NBLK_SIM*5]
#define TAILP_OFF (SIMP_OFF + NBLK_SIM * 5)   // float[W_BLK*4]
#define ICTRL     (TAILP_OFF + W_BLK * 4)     // int region base
// ctrl ints:
#define H2_OFF 0                      // 4*2048
#define H3_OFF 8192                   // 4*1024
#define CNT_OFF 12288
#define ST_OFF  12296
#define SF_OFF  12320
#define ZTOT    12289
#define H1R_OFF 12352                 // 16 rows x 2048 ints (written AFTER sim)
// prep region OVERLAYS H1R (prep consumed by sim; H1R written by hist1 post-sim)
#define PREP_OFF (ICTRL + H1R_OFF)
#define PSTR 1056                     // per-step dwords: A2 512 | A3 512 | L1p 24 | pad
#define HEADO (19 * PSTR)             // Wu0m[8], bu0m[8]  (prep total 20080 < 32768)

// ---------------- types / helpers ----------------
typedef float f32x16 __attribute__((ext_vector_type(16)));
typedef short bf16x8 __attribute__((ext_vector_type(8)));
union F8  { int4 i; bf16x8 b; };
union BFR { unsigned u[4]; int4 i; bf16x8 b; };

__device__ __forceinline__ unsigned pkbf(float lo, float hi) {
    __hip_bfloat162 t = __float22bfloat162_rn(make_float2(lo, hi));  // x=lo(low16), y=hi(high16)
    unsigned r;
    __builtin_memcpy(&r, &t, 4);
    return r;
}
__device__ __forceinline__ float bflo(unsigned u) { return __uint_as_float(u << 16); }
__device__ __forceinline__ float bfhi(unsigned u) { return __uint_as_float(u & 0xffff0000u); }
__device__ __forceinline__ unsigned fkey(float f) {
    unsigned u = __float_as_uint(f);
    return (u & 0x80000000u) ? ~u : (u | 0x80000000u);
}
__device__ __forceinline__ float funkey(unsigned k) {
    return __uint_as_float((k & 0x80000000u) ? (k ^ 0x80000000u) : ~k);
}
__device__ __forceinline__ float wred(float v) {
#pragma unroll
    for (int o = 32; o > 0; o >>= 1) v += __shfl_down(v, o);
    return v;
}
__device__ __forceinline__ unsigned short f2bf(float f) {   // RNE
    unsigned u = __float_as_uint(f);
    unsigned r = u + 0x7fffu + ((u >> 16) & 1u);
    return (unsigned short)(r >> 16);
}

__global__ void zero_kernel(int* __restrict__ ctrl) {
    int i = blockIdx.x * blockDim.x + threadIdx.x;
    if (i < ZTOT) ctrl[i] = 0;
}

// ---------------- prep: swizzle weights into MFMA fragment order ----------------
// k-slot labeling (32x32x16 bf16): lane l, dword v, half h:
//   k = 16c + 8*(v>>1) + 4*(l>>5) + 2*(v&1) + h ; A row / B col = l&31
// Bias fold: A k-slot 20 (c=1, g=1, v=0, lo) holds b2/b3; B k-slot 20 holds 1.0.
__global__ void prep_kernel(const float* __restrict__ Wu0, const float* __restrict__ bu0,
                            const float* __restrict__ W1, const float* __restrict__ b1,
                            const float* __restrict__ W2, const float* __restrict__ b2,
                            const float* __restrict__ W3, const float* __restrict__ b3,
                            float* __restrict__ prepF)
{
    const int s = blockIdx.x, tid = threadIdx.x;
    int* prepI = (int*)prepF;
    if (s < 19) {
        for (int t = tid; t < 512; t += 256) {
            int c = t >> 8, l = (t >> 2) & 63, v = t & 3;
            int g = l >> 5, row = l & 31;
            int kb = 16 * c + 8 * (v >> 1) + 4 * g + 2 * (v & 1);
            float lo = 0.f, hi = 0.f, lo3 = 0.f, hi3 = 0.f;
            if (row < 20) {
                if (kb < 20)       lo = W2[s * 400 + kb * 20 + row];
                else if (kb == 20) lo = b2[s * 20 + row];
                if (kb + 1 < 20)   hi = W2[s * 400 + (kb + 1) * 20 + row];
            }
            if (row < 5) {
                if (kb < 20)       lo3 = W3[s * 100 + kb * 5 + row];
                else if (kb == 20) lo3 = b3[s * 5 + row];
                if (kb + 1 < 20)   hi3 = W3[s * 100 + (kb + 1) * 5 + row];
            }
            prepI[s * PSTR + c * 256 + l * 4 + v]       = (int)(((unsigned)f2bf(hi)  << 16) | f2bf(lo));
            prepI[s * PSTR + 512 + c * 256 + l * 4 + v] = (int)(((unsigned)f2bf(hi3) << 16) | f2bf(lo3));
        }
        if (tid < 24) {   // L1 packed bf16 (w lo, b hi), neuron order per B k-slot map
            int g = tid / 12, j = tid % 12;
            int n = (j < 4) ? 4 * g + j : (j < 8) ? 8 + 4 * g + (j - 4) : 16 + 4 * g + (j - 8);
            unsigned w = 0, b = 0;
            if (n < 20) { w = f2bf(W1[s * 20 + n]); b = f2bf(b1[s * 20 + n]); }
            prepI[s * PSTR + 1024 + tid] = (int)((b << 16) | w);
        }
    } else {
        if (tid < 8) {    // Wu0/bu0 mapped to alpha C-regs 0-3 per g (d = r + 4g)
            int g = tid >> 2, r = tid & 3, d = r + 4 * g;
            prepF[HEADO + tid]     = (d < 5) ? Wu0[d] : 0.f;
            prepF[HEADO + 8 + tid] = (d < 5) ? bu0[d] : 0.f;
        }
    }
}

// ---------------- sim: MFMA MLP, 32 paths/wave, 1-step fragment prefetch ----------------
__global__ __launch_bounds__(THB, 2) void sim_kernel(
    const float* __restrict__ x_in, const float* __restrict__ dW,
    const float* __restrict__ Wo, const float* __restrict__ bo,
    const float* __restrict__ Wk, const float* __restrict__ bk,
    float* __restrict__ ws, int* __restrict__ ctrl, float* __restrict__ out,
    const float* __restrict__ prepF)
{
    __shared__ float red[4][5];
    __shared__ int lastF;
    const int tid = threadIdx.x;
    const int l = tid & 63;
    const int g = l >> 5;
    const bool gm = (g == 0);
    const int p = blockIdx.x * 128 + (tid >> 6) * 32 + (l & 31);

    float x = x_in[p];

    // softmax head
    float z[11], zm = -1e30f;
#pragma unroll
    for (int j = 0; j < 11; j++) {
        z[j] = fmaf(x, Wo[j], bo[j]);
        zm = fmaxf(zm, z[j]);
    }
    float se = 0.f;
#pragma unroll
    for (int j = 0; j < 11; j++) se += __expf(z[j] - zm);
    float smv = __expf(z[10] - zm) / se;

    float K0 = 1.f + 0.25f * tanhf(fmaf(x, Wk[0], bk[0]));

    // alpha in layer-3 C-layout: reg r -> asset r+4g (g1 r>0 -> exact 0)
    float a[4];
    {
        float4 w4 = *(const float4*)(prepF + HEADO + g * 4);
        float4 b4 = *(const float4*)(prepF + HEADO + 8 + g * 4);
        a[0] = fmaf(x, w4.x, b4.x); a[1] = fmaf(x, w4.y, b4.y);
        a[2] = fmaf(x, w4.z, b4.z); a[3] = fmaf(x, w4.w, b4.w);
    }
    float S[4] = {1.f, 1.f, 1.f, 1.f}, Nm1[4], dwb[4];
    float SQ0 = 1.f, dNs = 0.f;
#pragma unroll
    for (int e = 0; e < 4; e++) Nm1[e] = a[e];

    {   // dW lane slots: g0 -> d0..3, g1 -> d4,0,0,0 (scalar dword loads)
        const float* pw = dW + (size_t)p * 5;
        float d0 = pw[0], d1 = pw[1], d2v = pw[2], d3v = pw[3], d4 = pw[4];
        dwb[0] = gm ? d0 : d4;
        dwb[1] = gm ? d1 : 0.f; dwb[2] = gm ? d2v : 0.f; dwb[3] = gm ? d3v : 0.f;
    }

    // ---- preload slice 0 fragments into registers ----
    int4 cA20, cA21, cA30, cA31, cL0, cL1, cL2;
    {
        const float* sb = prepF;
        const int4* a2p = (const int4*)sb + l;          cA20 = a2p[0]; cA21 = a2p[64];
        const int4* a3p = (const int4*)(sb + 512) + l;  cA30 = a3p[0]; cA31 = a3p[64];
        const int4* lp  = (const int4*)(sb + 1024) + g * 3; cL0 = lp[0]; cL1 = lp[1]; cL2 = lp[2];
    }

    f32x16 zv;
#pragma unroll
    for (int i = 0; i < 16; i++) zv[i] = 0.f;

#pragma unroll 1
    for (int n = 1; n <= NST; n++) {
        // ---- issue next slice's fragment loads (consumed next iteration) ----
        int4 nA20, nA21, nA30, nA31, nL0, nL1, nL2;
        if (n < NST - 1) {
            const float* sb2 = prepF + n * PSTR;
            const int4* a2p = (const int4*)sb2 + l;          nA20 = a2p[0]; nA21 = a2p[64];
            const int4* a3p = (const int4*)(sb2 + 512) + l;  nA30 = a3p[0]; nA31 = a3p[64];
            const int4* lp  = (const int4*)(sb2 + 1024) + g * 3; nL0 = lp[0]; nL1 = lp[1]; nL2 = lp[2];
        }
        float dwc[4];
#pragma unroll
        for (int e = 0; e < 4; e++) dwc[e] = dwb[e];
        if (n < NST) {   // prefetch next step's noise
            const float* pw = dW + ((size_t)n * BB + p) * 5;
            float d0 = pw[0], d1 = pw[1], d2v = pw[2], d3v = pw[3], d4 = pw[4];
            dwb[0] = gm ? d0 : d4;
            dwb[1] = gm ? d1 : 0.f; dwb[2] = gm ? d2v : 0.f; dwb[3] = gm ? d3v : 0.f;
        }
        // Euler step (per-lane 4 asset slots; g1 extra slots are exact zeros)
        float du = 0.f, us = 0.f;
#pragma unroll
        for (int e = 0; e < 4; e++) {
            float f = fmaf(SIGc, dwc[e], BHc);
            du = fmaf(a[e], f, du);
            us += a[e];
            float Np = a[e] * __builtin_amdgcn_rcpf(S[e]);
            dNs += fabsf(Np - Nm1[e]);
            Nm1[e] = Np;
            S[e] = fmaf(S[e], f, S[e]);          // S *= 1 + BH + SIG*dw
        }
        SQ0 = fmaf(SQ0, fmaf(SIGc, dwc[0], RHc), SQ0);
        du += __shfl_xor(du, 32);
        us += __shfl_xor(us, 32);
        x = fmaf(x - us, RHc, x) + du;

        if (n < NST) {
            // ---- layer 1 from packed bf16 (w lo, b hi) ----
            float h[12];
            {
                unsigned u;
                u = (unsigned)cL0.x; h[0]  = fmaxf(fmaf(x, bflo(u), bfhi(u)), 0.f);
                u = (unsigned)cL0.y; h[1]  = fmaxf(fmaf(x, bflo(u), bfhi(u)), 0.f);
                u = (unsigned)cL0.z; h[2]  = fmaxf(fmaf(x, bflo(u), bfhi(u)), 0.f);
                u = (unsigned)cL0.w; h[3]  = fmaxf(fmaf(x, bflo(u), bfhi(u)), 0.f);
                u = (unsigned)cL1.x; h[4]  = fmaxf(fmaf(x, bflo(u), bfhi(u)), 0.f);
                u = (unsigned)cL1.y; h[5]  = fmaxf(fmaf(x, bflo(u), bfhi(u)), 0.f);
                u = (unsigned)cL1.z; h[6]  = fmaxf(fmaf(x, bflo(u), bfhi(u)), 0.f);
                u = (unsigned)cL1.w; h[7]  = fmaxf(fmaf(x, bflo(u), bfhi(u)), 0.f);
                u = (unsigned)cL2.x; h[8]  = fmaxf(fmaf(x, bflo(u), bfhi(u)), 0.f);
                u = (unsigned)cL2.y; h[9]  = fmaxf(fmaf(x, bflo(u), bfhi(u)), 0.f);
                u = (unsigned)cL2.z; h[10] = fmaxf(fmaf(x, bflo(u), bfhi(u)), 0.f);
                u = (unsigned)cL2.w; h[11] = fmaxf(fmaf(x, bflo(u), bfhi(u)), 0.f);
            }
            BFR b1c0, b1c1;
            b1c0.u[0] = pkbf(h[0], h[1]);  b1c0.u[1] = pkbf(h[2], h[3]);
            b1c0.u[2] = pkbf(h[4], h[5]);  b1c0.u[3] = pkbf(h[6], h[7]);
            b1c1.u[0] = gm ? pkbf(h[8], h[9])   : 0x00003F80u;  // g1 k-slot20 = 1.0 (bias row)
            b1c1.u[1] = gm ? pkbf(h[10], h[11]) : 0u;
            b1c1.u[2] = 0u; b1c1.u[3] = 0u;
            // ---- layer 2: D2 = W2^T * h1 (+ b2 via k-slot 20) ----
            F8 fa;
            fa.i = cA20;
            f32x16 d2 = __builtin_amdgcn_mfma_f32_32x32x16_bf16(fa.b, b1c0.b, zv, 0, 0, 0);
            fa.i = cA21;
            d2 = __builtin_amdgcn_mfma_f32_32x32x16_bf16(fa.b, b1c1.b, d2, 0, 0, 0);
            float h2r[12];
#pragma unroll
            for (int i = 0; i < 12; i++) h2r[i] = fmaxf(d2[i], 0.f);
            // ---- repack h2 C-layout -> layer-3 B-fragments (no cross-lane) ----
            BFR b2c0, b2c1;
            b2c0.u[0] = pkbf(h2r[0], h2r[1]); b2c0.u[1] = pkbf(h2r[2], h2r[3]);
            b2c0.u[2] = pkbf(h2r[4], h2r[5]); b2c0.u[3] = pkbf(h2r[6], h2r[7]);
            b2c1.u[0] = gm ? pkbf(h2r[8], h2r[9])   : 0x00003F80u;
            b2c1.u[1] = gm ? pkbf(h2r[10], h2r[11]) : 0u;
            b2c1.u[2] = 0u; b2c1.u[3] = 0u;
            // ---- layer 3: D3 = W3^T * h2 (+ b3 via k-slot 20) ----
            fa.i = cA30;
            f32x16 d3 = __builtin_amdgcn_mfma_f32_32x32x16_bf16(fa.b, b2c0.b, zv, 0, 0, 0);
            fa.i = cA31;
            d3 = __builtin_amdgcn_mfma_f32_32x32x16_bf16(fa.b, b2c1.b, d3, 0, 0, 0);
            a[0] = d3[0]; a[1] = d3[1]; a[2] = d3[2]; a[3] = d3[3];
        }
        if (n < NST - 1) {   // rotate pipeline registers (waitcnt for n* lands here)
            cA20 = nA20; cA21 = nA21; cA30 = nA30; cA31 = nA31;
            cL0 = nL0; cL1 = nL1; cL2 = nL2;
        }
    }

    // epilogue
    float dnO = __shfl_xor(dNs, 32);
    float xx = fmaf(-CURTc, dNs + dnO, x);
    if (gm) ws[p] = xx;
    float v0 = gm ? xx : 0.f;
    float v1 = gm ? xx * xx : 0.f;
    float v2 = gm ? fmaxf(S[0] - K0, 0.f) : 0.f;
    float v3 = gm ? fmaxf(SQ0 - K0, 0.f) : 0.f;
    float v4 = gm ? smv : 0.f;

    v0 = wred(v0); v1 = wred(v1); v2 = wred(v2); v3 = wred(v3); v4 = wred(v4);
    int wid = tid >> 6, lane = tid & 63;
    if (lane == 0) { red[wid][0] = v0; red[wid][1] = v1; red[wid][2] = v2; red[wid][3] = v3; red[wid][4] = v4; }
    __syncthreads();
    if (tid == 0) {
        float s0 = 0, s1 = 0, s2 = 0, s3 = 0, s4 = 0;
#pragma unroll
        for (int w = 0; w < 4; w++) { s0 += red[w][0]; s1 += red[w][1]; s2 += red[w][2]; s3 += red[w][3]; s4 += red[w][4]; }
        float* part = ws + SIMP_OFF + blockIdx.x * 5;
        part[0] = s0; part[1] = s1; part[2] = s2; part[3] = s3; part[4] = s4;
    }
    __threadfence();
    if (tid == 0) lastF = (atomicAdd(&ctrl[CNT_OFF], 1) == NBLK_SIM - 1);
    __syncthreads();
    if (!lastF) return;
    __threadfence();

    const float* part = ws + SIMP_OFF;
    float a0 = 0, a1 = 0, a2 = 0, a3 = 0, a4 = 0;
    for (int r = tid; r < NBLK_SIM; r += THB) {
        const float* pr = part + r * 5;
        a0 += pr[0]; a1 += pr[1]; a2 += pr[2]; a3 += pr[3]; a4 += pr[4];
    }
    a0 = wred(a0); a1 = wred(a1); a2 = wred(a2); a3 = wred(a3); a4 = wred(a4);
    if (lane == 0) { red[wid][0] = a0; red[wid][1] = a1; red[wid][2] = a2; red[wid][3] = a3; red[wid][4] = a4; }
    __syncthreads();
    if (tid == 0) {
        float Sx = 0, Sx2 = 0, SP = 0, SQs = 0, Ssm = 0;
#pragma unroll
        for (int w = 0; w < 4; w++) { Sx += red[w][0]; Sx2 += red[w][1]; SP += red[w][2]; SQs += red[w][3]; Ssm += red[w][4]; }
        float invB = 1.f / (float)BB;
        float meanx = Sx * invB;
        out[0] = -meanx;
        out[1] = Sx2 * invB - meanx * meanx;
        out[4] = (SP * invB) / (DISCf * (SQs * invB) + 1e-8f);
        out[5] = 1.f + 0.25f * tanhf(fmaf(x_in[0], Wk[1], bk[1]));
        out[6] = Ssm * invB;
    }
}

// ---------------- select helpers ----------------
__device__ __forceinline__ void aggAdd(int* h, int code) {
    bool act = (code >= 0);
    unsigned long long mask = __ballot(act);
    while (mask) {
        int leader = __ffsll((unsigned long long)mask) - 1;
        int lc = __shfl(code, leader);
        unsigned long long mm = __ballot(act && code == lc);
        if ((threadIdx.x & 63) == leader) atomicAdd(&h[lc], (int)__popcll(mm));
        mask &= ~mm;
    }
}

__device__ int excl_scan1024(int v, int tid, int* wsum) {
    __syncthreads();
    int lane = tid & 63, wid = tid >> 6;
    int inc = v;
#pragma unroll
    for (int o = 1; o < 64; o <<= 1) { int u = __shfl_up(inc, o); if (lane >= o) inc += u; }
    if (lane == 63) wsum[wid] = inc;
    __syncthreads();
    if (tid < 16) {
        int wv = wsum[tid], winc = wv;
#pragma unroll
        for (int o = 1; o < 16; o <<= 1) { int u = __shfl_up(winc, o); if (tid >= o) winc += u; }
        wsum[tid] = winc - wv;
    }
    __syncthreads();
    return wsum[wid] + inc - v;
}

__global__ __launch_bounds__(H1_THR) void hist1_kernel(const float* __restrict__ xf,
                                                       int* __restrict__ ctrl)
{
    __shared__ int lh[2048];
    const int tid = threadIdx.x, bl = blockIdx.x;
    for (int i = tid; i < 2048; i += H1_THR) lh[i] = 0;
    __syncthreads();
    const float4* xf4 = (const float4*)xf;
#pragma unroll
    for (int w = 0; w < 4; w++) {
        float4 v = xf4[(size_t)bl * 4096 + w * 1024 + tid];
        aggAdd(lh, (int)(fkey(v.x) >> 21));
        aggAdd(lh, (int)(fkey(v.y) >> 21));
        aggAdd(lh, (int)(fkey(v.z) >> 21));
        aggAdd(lh, (int)(fkey(v.w) >> 21));
    }
    __syncthreads();
    int* row = ctrl + H1R_OFF + bl * 2048;
    for (int i = tid; i < 2048; i += H1_THR) row[i] = lh[i];
}

__global__ __launch_bounds__(1024) void scan1_kernel(int* __restrict__ ctrl)
{
    __shared__ int wsum[16];
    __shared__ int binT[4], remT[4];
    const int tid = threadIdx.x;
    const int* rows = ctrl + H1R_OFF;
    int c0 = 0, c1 = 0;
    for (int r = 0; r < H1_BLK; r++) {
        c0 += rows[r * 2048 + 2 * tid];
        c1 += rows[r * 2048 + 2 * tid + 1];
    }
    int s = c0 + c1;
    int E = excl_scan1024(s, tid, wsum);
    const int RK[4] = {13107, 13108, 249035, 249036};
#pragma unroll
    for (int t = 0; t < 4; t++) {
        int r = RK[t];
        if (r >= E && r < E + s) {
            if (r < E + c0) { binT[t] = 2 * tid;     remT[t] = r - E; }
            else            { binT[t] = 2 * tid + 1; remT[t] = r - E - c0; }
        }
    }
    __syncthreads();
    if (tid == 0) {
        for (int t = 0; t < 4; t++) { ctrl[ST_OFF + t] = binT[t]; ctrl[ST_OFF + 4 + t] = remT[t]; }
        for (int t = 0; t < 4; t++) {
            int g = t;
            for (int q = 0; q < t; q++) if (binT[q] == binT[t]) { g = q; break; }
            ctrl[ST_OFF + 8 + t] = g;
        }
    }
}

__global__ __launch_bounds__(W_THR) void hist2_kernel(const float* __restrict__ xf,
                                                      int* __restrict__ ctrl)
{
    const int tid = threadIdx.x, bl = blockIdx.x;
    int pf[4], gp[4];
#pragma unroll
    for (int t = 0; t < 4; t++) { pf[t] = ctrl[ST_OFF + t]; gp[t] = ctrl[ST_OFF + 8 + t]; }
    float4 v = ((const float4*)xf)[(size_t)bl * W_THR + tid];
    float xv[4] = {v.x, v.y, v.z, v.w};
#pragma unroll
    for (int k = 0; k < 4; k++) {
        unsigned u = fkey(xv[k]);
        unsigned hi = u >> 21;
        int bin = (int)((u >> 10) & 2047u);
        int code = -1;
#pragma unroll
        for (int t = 0; t < 4; t++)
            if (gp[t] == t && (unsigned)pf[t] == hi) code = t * 2048 + bin;
        aggAdd(ctrl + H2_OFF, code);
    }
}

__global__ __launch_bounds__(1024) void scan2_kernel(int* __restrict__ ctrl)
{
    __shared__ int wsum[16];
    __shared__ int binT[4], remT[4];
    const int tid = threadIdx.x;
    for (int t = 0; t < 4; t++) {
        int g = ctrl[ST_OFF + 8 + t], rank = ctrl[ST_OFF + 4 + t];
        const int* h = ctrl + H2_OFF + g * 2048;
        int c0 = h[2 * tid], c1 = h[2 * tid + 1];
        int s = c0 + c1;
        int E = excl_scan1024(s, tid, wsum);
        if (rank >= E && rank < E + s) {
            if (rank < E + c0) { binT[t] = 2 * tid;     remT[t] = rank - E; }
            else               { binT[t] = 2 * tid + 1; remT[t] = rank - E - c0; }
        }
        __syncthreads();
    }
    if (tid == 0) {
        int P2n[4];
        for (int t = 0; t < 4; t++) {
            P2n[t] = (ctrl[ST_OFF + t] << 11) | binT[t];
            ctrl[ST_OFF + 12 + t] = P2n[t];
            ctrl[ST_OFF + 16 + t] = remT[t];
        }
        for (int t = 0; t < 4; t++) {
            int g = t;
            for (int q = 0; q < t; q++) if (P2n[q] == P2n[t]) { g = q; break; }
            ctrl[ST_OFF + 20 + t] = g;
        }
    }
}

__global__ __launch_bounds__(W_THR) void hist3_kernel(const float* __restrict__ xf,
                                                      int* __restrict__ ctrl)
{
    const int tid = threadIdx.x, bl = blockIdx.x;
    int pf[4], gp[4];
#pragma unroll
    for (int t = 0; t < 4; t++) { pf[t] = ctrl[ST_OFF + 12 + t]; gp[t] = ctrl[ST_OFF + 20 + t]; }
    float4 v = ((const float4*)xf)[(size_t)bl * W_THR + tid];
    float xv[4] = {v.x, v.y, v.z, v.w};
#pragma unroll
    for (int k = 0; k < 4; k++) {
        unsigned u = fkey(xv[k]);
        unsigned hi = u >> 10;
        int bin = (int)(u & 1023u);
        int code = -1;
#pragma unroll
        for (int t = 0; t < 4; t++)
            if (gp[t] == t && (unsigned)pf[t] == hi) code = t * 1024 + bin;
        aggAdd(ctrl + H3_OFF, code);
    }
}

__global__ __launch_bounds__(1024) void scan3_kernel(int* __restrict__ ctrl)
{
    __shared__ int wsum[16];
    __shared__ int binT[4];
    const int tid = threadIdx.x;
    for (int t = 0; t < 4; t++) {
        int g = ctrl[ST_OFF + 20 + t], rank = ctrl[ST_OFF + 16 + t];
        const int* h = ctrl + H3_OFF + g * 1024;
        int s = h[tid];
        int E = excl_scan1024(s, tid, wsum);
        if (rank >= E && rank < E + s) binT[t] = tid;
        __syncthreads();
    }
    if (tid == 0) {
        float* sf = (float*)(ctrl + SF_OFF);
        float v[4];
        for (int t = 0; t < 4; t++) {
            unsigned key = ((unsigned)ctrl[ST_OFF + 12 + t] << 10) | (unsigned)binT[t];
            v[t] = funkey(key);
            sf[t] = v[t];
        }
        sf[4] = v[0] + 0.15f * (v[1] - v[0]);  // p5  (idx 0.05*(B-1)=13107.15)
        sf[5] = v[2] + 0.85f * (v[3] - v[2]);  // p95 (idx 0.95*(B-1)=249035.85)
    }
}

__global__ __launch_bounds__(W_THR) void tail_kernel(const float* __restrict__ xf,
                                                     const int* __restrict__ ctrl,
                                                     float* __restrict__ ws)
{
    __shared__ float frd[4][4];
    const int tid = threadIdx.x, bl = blockIdx.x;
    const float* sf = (const float*)(ctrl + SF_OFF);
    const float p5 = sf[4], p95 = sf[5];
    float4 v = ((const float4*)xf)[(size_t)bl * W_THR + tid];
    float xv[4] = {v.x, v.y, v.z, v.w};
    float slo = 0.f, clo = 0.f, shi = 0.f, chi = 0.f;
#pragma unroll
    for (int k = 0; k < 4; k++) {
        float x = xv[k];
        if (x < p5)  { slo += x; clo += 1.f; }
        if (x > p95) { shi += x; chi += 1.f; }
    }
    slo = wred(slo); clo = wred(clo); shi = wred(shi); chi = wred(chi);
    int wid = tid >> 6, lane = tid & 63;
    if (lane == 0) { frd[wid][0] = slo; frd[wid][1] = clo; frd[wid][2] = shi; frd[wid][3] = chi; }
    __syncthreads();
    if (tid == 0) {
        float s0 = 0, s1 = 0, s2 = 0, s3 = 0;
#pragma unroll
        for (int w = 0; w < 4; w++) { s0 += frd[w][0]; s1 += frd[w][1]; s2 += frd[w][2]; s3 += frd[w][3]; }
        float* tp = ws + TAILP_OFF + bl * 4;
        tp[0] = s0; tp[1] = s1; tp[2] = s2; tp[3] = s3;
    }
}

__global__ __launch_bounds__(256) void tailfin_kernel(const float* __restrict__ ws,
                                                      float* __restrict__ out)
{
    __shared__ float frd[4][4];
    const int tid = threadIdx.x;
    const float* tp = ws + TAILP_OFF;
    float a0 = tp[tid * 4 + 0], a1 = tp[tid * 4 + 1], a2 = tp[tid * 4 + 2], a3 = tp[tid * 4 + 3];
    a0 = wred(a0); a1 = wred(a1); a2 = wred(a2); a3 = wred(a3);
    int wid = tid >> 6, lane = tid & 63;
    if (lane == 0) { frd[wid][0] = a0; frd[wid][1] = a1; frd[wid][2] = a2; frd[wid][3] = a3; }
    __syncthreads();
    if (tid == 0) {
        float Slo = 0, Clo = 0, Shi = 0, Chi = 0;
#pragma unroll
        for (int w = 0; w < 4; w++) { Slo += frd[w][0]; Clo += frd[w][1]; Shi += frd[w][2]; Chi += frd[w][3]; }
        out[2] = -Slo / fmaxf(Clo, 1.f);
        out[3] = -Shi / fmaxf(Chi, 1.f);
    }
}

// ---------------- host ----------------
extern "C" void kernel_launch(void* const* d_in, const int* in_sizes, int n_in,
                              void* d_out, int out_size, void* d_ws, size_t ws_size,
                              hipStream_t stream)
{
    const float* x_in = (const float*)d_in[0];
    const float* dW   = (const float*)d_in[1];
    const float* Wo   = (const float*)d_in[2];
    const float* bo   = (const float*)d_in[3];
    const float* Wk   = (const float*)d_in[4];
    const float* bk   = (const float*)d_in[5];
    const float* Wu0  = (const float*)d_in[6];
    const float* bu0  = (const float*)d_in[7];
    const float* W1   = (const float*)d_in[8];
    const float* b1   = (const float*)d_in[9];
    const float* W2   = (const float*)d_in[10];
    const float* b2   = (const float*)d_in[11];
    const float* W3   = (const float*)d_in[12];
    const float* b3   = (const float*)d_in[13];
    float* ws   = (float*)d_ws;
    int* ctrl   = (int*)d_ws + ICTRL;
    float* prep = ws + PREP_OFF;
    float* out  = (float*)d_out;

    zero_kernel<<<(ZTOT + 1023) / 1024, 1024, 0, stream>>>(ctrl);
    prep_kernel<<<20, 256, 0, stream>>>(Wu0, bu0, W1, b1, W2, b2, W3, b3, prep);
    sim_kernel<<<NBLK_SIM, THB, 0, stream>>>(x_in, dW, Wo, bo, Wk, bk, ws, ctrl, out, prep);
    hist1_kernel<<<H1_BLK, H1_THR, 0, stream>>>(ws, ctrl);
    scan1_kernel<<<1, 1024, 0, stream>>>(ctrl);
    hist2_kernel<<<W_BLK, W_THR, 0, stream>>>(ws, ctrl);
    scan2_kernel<<<1, 1024, 0, stream>>>(ctrl);
    hist3_kernel<<<W_BLK, W_THR, 0, stream>>>(ws, ctrl);
    scan3_kernel<<<1, 1024, 0, stream>>>(ctrl);
    tail_kernel<<<W_BLK, W_THR, 0, stream>>>(ws, ctrl, ws);
    tailfin_kernel<<<1, 256, 0, stream>>>(ws, out);
}

// Round 9
// 276.880 us; speedup vs baseline: 1.2738x; 1.2342x over previous
//
#include <hip/hip_runtime.h>
#include <hip/hip_bf16.h>
#include <math.h>

// ---------------- problem constants ----------------
#define BB 262144
#define NST 20
#define RHc 0.006f            // R*H
#define BHc 0.01f             // B_DRIFT*H
#define SIGc 0.2f
#define CURTc 0.005f
#define DISCf 0.8869204367171575f   // exp(-0.12)

// ---------------- launch geometry ----------------
#define THB_SIM 512
#define NBLK_SIM 1024          // 256 paths per block (8 waves x 32)
#define H1_BLK 16
#define H1_THR 1024
#define W_BLK 256
#define W_THR 256

// ---------------- workspace layout (floats from ws base unless noted) ----------------
#define SIMP_OFF  BB                          // float[NBLK_SIM*5]
#define TAILP_OFF (SIMP_OFF + NBLK_SIM * 5)   // float[W_BLK*4]
#define ICTRL     (TAILP_OFF + W_BLK * 4)     // int region base (BB+6144, %4==0)
// ctrl ints:
#define H2_OFF 0                      // 4*2048
#define H3_OFF 8192                   // 4*1024
#define CNT_OFF 12288
#define ST_OFF  12296
#define SF_OFF  12320
#define ZTOT    12289
#define H1R_OFF 12352                 // 16 rows x 2048 ints (written AFTER sim)
// prep region OVERLAYS H1R (prep consumed by sim; H1R written by hist1 post-sim)
#define PREP_OFF (ICTRL + H1R_OFF)    // %4==0 -> 16B aligned
#define PSTR 1056                     // per-step dwords: A2 512 | A3 512 | L1p 24 | pad
#define HEADO (19 * PSTR)             // =20064; Wu0m[8], bu0m[8] follow
#define PREP_I4 5016                  // int4 count staged to LDS (=HEADO/4)

// ---------------- types / helpers ----------------
typedef float f32x16 __attribute__((ext_vector_type(16)));
typedef short bf16x8 __attribute__((ext_vector_type(8)));
union F8  { int4 i; bf16x8 b; };
union BFR { unsigned u[4]; int4 i; bf16x8 b; };

__device__ __forceinline__ unsigned pkbf(float lo, float hi) {   // 1 VALU op
    unsigned r;
    asm("v_cvt_pk_bf16_f32 %0, %1, %2" : "=v"(r) : "v"(lo), "v"(hi));
    return r;
}
__device__ __forceinline__ float bflo(unsigned u) { return __uint_as_float(u << 16); }
__device__ __forceinline__ float bfhi(unsigned u) { return __uint_as_float(u & 0xffff0000u); }
__device__ __forceinline__ unsigned fkey(float f) {
    unsigned u = __float_as_uint(f);
    return (u & 0x80000000u) ? ~u : (u | 0x80000000u);
}
__device__ __forceinline__ float funkey(unsigned k) {
    return __uint_as_float((k & 0x80000000u) ? (k ^ 0x80000000u) : ~k);
}
__device__ __forceinline__ float wred(float v) {
#pragma unroll
    for (int o = 32; o > 0; o >>= 1) v += __shfl_down(v, o);
    return v;
}
__device__ __forceinline__ unsigned short f2bf(float f) {   // RNE
    unsigned u = __float_as_uint(f);
    unsigned r = u + 0x7fffu + ((u >> 16) & 1u);
    return (unsigned short)(r >> 16);
}

__global__ void zero_kernel(int* __restrict__ ctrl) {
    int i = blockIdx.x * blockDim.x + threadIdx.x;
    if (i < ZTOT) ctrl[i] = 0;
}

// ---------------- prep: swizzle weights into MFMA fragment order ----------------
// k-slot labeling (32x32x16 bf16): lane l, dword v, half h:
//   k = 16c + 8*(v>>1) + 4*(l>>5) + 2*(v&1) + h ; A row / B col = l&31
// Bias fold: A k-slot 20 holds b2/b3; B k-slot 20 holds 1.0.
__global__ void prep_kernel(const float* __restrict__ Wu0, const float* __restrict__ bu0,
                            const float* __restrict__ W1, const float* __restrict__ b1,
                            const float* __restrict__ W2, const float* __restrict__ b2,
                            const float* __restrict__ W3, const float* __restrict__ b3,
                            float* __restrict__ prepF)
{
    const int s = blockIdx.x, tid = threadIdx.x;
    int* prepI = (int*)prepF;
    if (s < 19) {
        for (int t = tid; t < 512; t += 256) {
            int c = t >> 8, l = (t >> 2) & 63, v = t & 3;
            int g = l >> 5, row = l & 31;
            int kb = 16 * c + 8 * (v >> 1) + 4 * g + 2 * (v & 1);
            float lo = 0.f, hi = 0.f, lo3 = 0.f, hi3 = 0.f;
            if (row < 20) {
                if (kb < 20)       lo = W2[s * 400 + kb * 20 + row];
                else if (kb == 20) lo = b2[s * 20 + row];
                if (kb + 1 < 20)   hi = W2[s * 400 + (kb + 1) * 20 + row];
            }
            if (row < 5) {
                if (kb < 20)       lo3 = W3[s * 100 + kb * 5 + row];
                else if (kb == 20) lo3 = b3[s * 5 + row];
                if (kb + 1 < 20)   hi3 = W3[s * 100 + (kb + 1) * 5 + row];
            }
            prepI[s * PSTR + c * 256 + l * 4 + v]       = (int)(((unsigned)f2bf(hi)  << 16) | f2bf(lo));
            prepI[s * PSTR + 512 + c * 256 + l * 4 + v] = (int)(((unsigned)f2bf(hi3) << 16) | f2bf(lo3));
        }
        if (tid < 24) {   // L1 packed bf16 (w lo, b hi), neuron order per B k-slot map
            int g = tid / 12, j = tid % 12;
            int n = (j < 4) ? 4 * g + j : (j < 8) ? 8 + 4 * g + (j - 4) : 16 + 4 * g + (j - 8);
            unsigned w = 0, b = 0;
            if (n < 20) { w = f2bf(W1[s * 20 + n]); b = f2bf(b1[s * 20 + n]); }
            prepI[s * PSTR + 1024 + tid] = (int)((b << 16) | w);
        }
        if (tid >= 24 && tid < 32) prepI[s * PSTR + 1024 + tid] = 0;  // pad
    } else {
        if (tid < 8) {    // Wu0/bu0 mapped to alpha C-regs 0-3 per g (d = r + 4g)
            int g = tid >> 2, r = tid & 3, d = r + 4 * g;
            prepF[HEADO + tid]     = (d < 5) ? Wu0[d] : 0.f;
            prepF[HEADO + 8 + tid] = (d < 5) ? bu0[d] : 0.f;
        }
    }
}

// ---------------- sim: MFMA MLP, 32 paths/wave, fragments staged in LDS ----------------
__global__ __launch_bounds__(THB_SIM, 4) void sim_kernel(
    const float* __restrict__ x_in, const float* __restrict__ dW,
    const float* __restrict__ Wo, const float* __restrict__ bo,
    const float* __restrict__ Wk, const float* __restrict__ bk,
    float* __restrict__ ws, int* __restrict__ ctrl, float* __restrict__ out,
    const float* __restrict__ prepF)
{
    __shared__ int4 LsI[PREP_I4];      // 78.4 KiB -> LDS-limited 2 blocks/CU
    __shared__ float red[8][5];
    __shared__ int lastF;
    const int tid = threadIdx.x;
    const int l = tid & 63;
    const int g = l >> 5;
    const bool gm = (g == 0);
    const int p = blockIdx.x * 256 + (tid >> 6) * 32 + (l & 31);

    {   // stage all 19 steps' fragments into LDS (cannot be undone by regalloc)
        const int4* gp4 = (const int4*)prepF;
        for (int i = tid; i < PREP_I4; i += THB_SIM) LsI[i] = gp4[i];
    }
    const float* Ls = (const float*)LsI;

    float x = x_in[p];

    // softmax head
    float z[11], zm = -1e30f;
#pragma unroll
    for (int j = 0; j < 11; j++) {
        z[j] = fmaf(x, Wo[j], bo[j]);
        zm = fmaxf(zm, z[j]);
    }
    float se = 0.f;
#pragma unroll
    for (int j = 0; j < 11; j++) se += __expf(z[j] - zm);
    float smv = __expf(z[10] - zm) / se;

    float K0 = 1.f + 0.25f * tanhf(fmaf(x, Wk[0], bk[0]));

    // alpha in layer-3 C-layout: reg r -> asset r+4g (g1 r>0 -> exact 0); head from global
    float a[4];
    {
        float4 w4 = *(const float4*)(prepF + HEADO + g * 4);
        float4 b4 = *(const float4*)(prepF + HEADO + 8 + g * 4);
        a[0] = fmaf(x, w4.x, b4.x); a[1] = fmaf(x, w4.y, b4.y);
        a[2] = fmaf(x, w4.z, b4.z); a[3] = fmaf(x, w4.w, b4.w);
    }
    float S[4] = {1.f, 1.f, 1.f, 1.f}, Nm1[4], dwb[4];
    float SQ0 = 1.f, dNs = 0.f;
#pragma unroll
    for (int e = 0; e < 4; e++) Nm1[e] = a[e];

    {   // dW lane slots: g0 -> d0..3, g1 -> d4,0,0,0 (scalar dword loads)
        const float* pw = dW + (size_t)p * 5;
        float d0 = pw[0], d1 = pw[1], d2v = pw[2], d3v = pw[3], d4 = pw[4];
        dwb[0] = gm ? d0 : d4;
        dwb[1] = gm ? d1 : 0.f; dwb[2] = gm ? d2v : 0.f; dwb[3] = gm ? d3v : 0.f;
    }

    __syncthreads();   // LDS staging complete

    f32x16 zv;
#pragma unroll
    for (int i = 0; i < 16; i++) zv[i] = 0.f;

#pragma unroll 1
    for (int n = 1; n <= NST; n++) {
        float dwc[4];
#pragma unroll
        for (int e = 0; e < 4; e++) dwc[e] = dwb[e];
        if (n < NST) {   // prefetch next step's noise (regs now available for it)
            const float* pw = dW + ((size_t)n * BB + p) * 5;
            float d0 = pw[0], d1 = pw[1], d2v = pw[2], d3v = pw[3], d4 = pw[4];
            dwb[0] = gm ? d0 : d4;
            dwb[1] = gm ? d1 : 0.f; dwb[2] = gm ? d2v : 0.f; dwb[3] = gm ? d3v : 0.f;
        }
        // Euler step (per-lane 4 asset slots; g1 extra slots are exact zeros)
        float du = 0.f, us = 0.f;
#pragma unroll
        for (int e = 0; e < 4; e++) {
            float f = fmaf(SIGc, dwc[e], BHc);
            du = fmaf(a[e], f, du);
            us += a[e];
            float Np = a[e] * __builtin_amdgcn_rcpf(S[e]);
            dNs += fabsf(Np - Nm1[e]);
            Nm1[e] = Np;
            S[e] = fmaf(S[e], f, S[e]);          // S *= 1 + BH + SIG*dw
        }
        SQ0 = fmaf(SQ0, fmaf(SIGc, dwc[0], RHc), SQ0);
        du += __shfl_xor(du, 32);
        us += __shfl_xor(us, 32);
        x = fmaf(x - us, RHc, x) + du;

        if (n < NST) {
            const float* sb = Ls + (n - 1) * PSTR;
            // fragment LDS reads (conflict-free b128; scheduler overlaps with VALU)
            const int4* a2p = (const int4*)sb + l;
            const int4* a3p = (const int4*)(sb + 512) + l;
            const int4* lp  = (const int4*)(sb + 1024) + g * 3;
            int4 cL0 = lp[0], cL1 = lp[1], cL2 = lp[2];
            int4 cA20 = a2p[0], cA21 = a2p[64];
            int4 cA30 = a3p[0], cA31 = a3p[64];
            // ---- layer 1 from packed bf16 (w lo, b hi) ----
            float h[12];
            {
                unsigned u;
                u = (unsigned)cL0.x; h[0]  = fmaxf(fmaf(x, bflo(u), bfhi(u)), 0.f);
                u = (unsigned)cL0.y; h[1]  = fmaxf(fmaf(x, bflo(u), bfhi(u)), 0.f);
                u = (unsigned)cL0.z; h[2]  = fmaxf(fmaf(x, bflo(u), bfhi(u)), 0.f);
                u = (unsigned)cL0.w; h[3]  = fmaxf(fmaf(x, bflo(u), bfhi(u)), 0.f);
                u = (unsigned)cL1.x; h[4]  = fmaxf(fmaf(x, bflo(u), bfhi(u)), 0.f);
                u = (unsigned)cL1.y; h[5]  = fmaxf(fmaf(x, bflo(u), bfhi(u)), 0.f);
                u = (unsigned)cL1.z; h[6]  = fmaxf(fmaf(x, bflo(u), bfhi(u)), 0.f);
                u = (unsigned)cL1.w; h[7]  = fmaxf(fmaf(x, bflo(u), bfhi(u)), 0.f);
                u = (unsigned)cL2.x; h[8]  = fmaxf(fmaf(x, bflo(u), bfhi(u)), 0.f);
                u = (unsigned)cL2.y; h[9]  = fmaxf(fmaf(x, bflo(u), bfhi(u)), 0.f);
                u = (unsigned)cL2.z; h[10] = fmaxf(fmaf(x, bflo(u), bfhi(u)), 0.f);
                u = (unsigned)cL2.w; h[11] = fmaxf(fmaf(x, bflo(u), bfhi(u)), 0.f);
            }
            BFR b1c0, b1c1;
            b1c0.u[0] = pkbf(h[0], h[1]);  b1c0.u[1] = pkbf(h[2], h[3]);
            b1c0.u[2] = pkbf(h[4], h[5]);  b1c0.u[3] = pkbf(h[6], h[7]);
            b1c1.u[0] = gm ? pkbf(h[8], h[9])   : 0x00003F80u;  // g1 k-slot20 = 1.0 (bias)
            b1c1.u[1] = gm ? pkbf(h[10], h[11]) : 0u;
            b1c1.u[2] = 0u; b1c1.u[3] = 0u;
            // ---- layer 2: D2 = W2^T * h1 (+ b2 via k-slot 20) ----
            F8 fa;
            fa.i = cA20;
            f32x16 d2 = __builtin_amdgcn_mfma_f32_32x32x16_bf16(fa.b, b1c0.b, zv, 0, 0, 0);
            fa.i = cA21;
            d2 = __builtin_amdgcn_mfma_f32_32x32x16_bf16(fa.b, b1c1.b, d2, 0, 0, 0);
            float h2r[12];
#pragma unroll
            for (int i = 0; i < 12; i++) h2r[i] = fmaxf(d2[i], 0.f);
            // ---- repack h2 C-layout -> layer-3 B-fragments (no cross-lane) ----
            BFR b2c0, b2c1;
            b2c0.u[0] = pkbf(h2r[0], h2r[1]); b2c0.u[1] = pkbf(h2r[2], h2r[3]);
            b2c0.u[2] = pkbf(h2r[4], h2r[5]); b2c0.u[3] = pkbf(h2r[6], h2r[7]);
            b2c1.u[0] = gm ? pkbf(h2r[8], h2r[9])   : 0x00003F80u;
            b2c1.u[1] = gm ? pkbf(h2r[10], h2r[11]) : 0u;
            b2c1.u[2] = 0u; b2c1.u[3] = 0u;
            // ---- layer 3: D3 = W3^T * h2 (+ b3 via k-slot 20) ----
            fa.i = cA30;
            f32x16 d3 = __builtin_amdgcn_mfma_f32_32x32x16_bf16(fa.b, b2c0.b, zv, 0, 0, 0);
            fa.i = cA31;
            d3 = __builtin_amdgcn_mfma_f32_32x32x16_bf16(fa.b, b2c1.b, d3, 0, 0, 0);
            a[0] = d3[0]; a[1] = d3[1]; a[2] = d3[2]; a[3] = d3[3];
        }
    }

    // epilogue
    float dnO = __shfl_xor(dNs, 32);
    float xx = fmaf(-CURTc, dNs + dnO, x);
    if (gm) ws[p] = xx;
    float v0 = gm ? xx : 0.f;
    float v1 = gm ? xx * xx : 0.f;
    float v2 = gm ? fmaxf(S[0] - K0, 0.f) : 0.f;
    float v3 = gm ? fmaxf(SQ0 - K0, 0.f) : 0.f;
    float v4 = gm ? smv : 0.f;

    v0 = wred(v0); v1 = wred(v1); v2 = wred(v2); v3 = wred(v3); v4 = wred(v4);
    int wid = tid >> 6, lane = tid & 63;
    if (lane == 0) { red[wid][0] = v0; red[wid][1] = v1; red[wid][2] = v2; red[wid][3] = v3; red[wid][4] = v4; }
    __syncthreads();
    if (tid == 0) {
        float s0 = 0, s1 = 0, s2 = 0, s3 = 0, s4 = 0;
#pragma unroll
        for (int w = 0; w < 8; w++) { s0 += red[w][0]; s1 += red[w][1]; s2 += red[w][2]; s3 += red[w][3]; s4 += red[w][4]; }
        float* part = ws + SIMP_OFF + blockIdx.x * 5;
        part[0] = s0; part[1] = s1; part[2] = s2; part[3] = s3; part[4] = s4;
    }
    __threadfence();
    if (tid == 0) lastF = (atomicAdd(&ctrl[CNT_OFF], 1) == NBLK_SIM - 1);
    __syncthreads();
    if (!lastF) return;
    __threadfence();

    const float* part = ws + SIMP_OFF;
    float a0 = 0, a1 = 0, a2 = 0, a3 = 0, a4 = 0;
    for (int r = tid; r < NBLK_SIM; r += THB_SIM) {
        const float* pr = part + r * 5;
        a0 += pr[0]; a1 += pr[1]; a2 += pr[2]; a3 += pr[3]; a4 += pr[4];
    }
    a0 = wred(a0); a1 = wred(a1); a2 = wred(a2); a3 = wred(a3); a4 = wred(a4);
    if (lane == 0) { red[wid][0] = a0; red[wid][1] = a1; red[wid][2] = a2; red[wid][3] = a3; red[wid][4] = a4; }
    __syncthreads();
    if (tid == 0) {
        float Sx = 0, Sx2 = 0, SP = 0, SQs = 0, Ssm = 0;
#pragma unroll
        for (int w = 0; w < 8; w++) { Sx += red[w][0]; Sx2 += red[w][1]; SP += red[w][2]; SQs += red[w][3]; Ssm += red[w][4]; }
        float invB = 1.f / (float)BB;
        float meanx = Sx * invB;
        out[0] = -meanx;
        out[1] = Sx2 * invB - meanx * meanx;
        out[4] = (SP * invB) / (DISCf * (SQs * invB) + 1e-8f);
        out[5] = 1.f + 0.25f * tanhf(fmaf(x_in[0], Wk[1], bk[1]));
        out[6] = Ssm * invB;
    }
}

// ---------------- select helpers ----------------
__device__ __forceinline__ void aggAdd(int* h, int code) {
    bool act = (code >= 0);
    unsigned long long mask = __ballot(act);
    while (mask) {
        int leader = __ffsll((unsigned long long)mask) - 1;
        int lc = __shfl(code, leader);
        unsigned long long mm = __ballot(act && code == lc);
        if ((threadIdx.x & 63) == leader) atomicAdd(&h[lc], (int)__popcll(mm));
        mask &= ~mm;
    }
}

__device__ int excl_scan1024(int v, int tid, int* wsum) {
    __syncthreads();
    int lane = tid & 63, wid = tid >> 6;
    int inc = v;
#pragma unroll
    for (int o = 1; o < 64; o <<= 1) { int u = __shfl_up(inc, o); if (lane >= o) inc += u; }
    if (lane == 63) wsum[wid] = inc;
    __syncthreads();
    if (tid < 16) {
        int wv = wsum[tid], winc = wv;
#pragma unroll
        for (int o = 1; o < 16; o <<= 1) { int u = __shfl_up(winc, o); if (tid >= o) winc += u; }
        wsum[tid] = winc - wv;
    }
    __syncthreads();
    return wsum[wid] + inc - v;
}

__global__ __launch_bounds__(H1_THR) void hist1_kernel(const float* __restrict__ xf,
                                                       int* __restrict__ ctrl)
{
    __shared__ int lh[2048];
    const int tid = threadIdx.x, bl = blockIdx.x;
    for (int i = tid; i < 2048; i += H1_THR) lh[i] = 0;
    __syncthreads();
    const float4* xf4 = (const float4*)xf;
#pragma unroll
    for (int w = 0; w < 4; w++) {
        float4 v = xf4[(size_t)bl * 4096 + w * 1024 + tid];
        aggAdd(lh, (int)(fkey(v.x) >> 21));
        aggAdd(lh, (int)(fkey(v.y) >> 21));
        aggAdd(lh, (int)(fkey(v.z) >> 21));
        aggAdd(lh, (int)(fkey(v.w) >> 21));
    }
    __syncthreads();
    int* row = ctrl + H1R_OFF + bl * 2048;
    for (int i = tid; i < 2048; i += H1_THR) row[i] = lh[i];
}

__global__ __launch_bounds__(1024) void scan1_kernel(int* __restrict__ ctrl)
{
    __shared__ int wsum[16];
    __shared__ int binT[4], remT[4];
    const int tid = threadIdx.x;
    const int* rows = ctrl + H1R_OFF;
    int c0 = 0, c1 = 0;
    for (int r = 0; r < H1_BLK; r++) {
        c0 += rows[r * 2048 + 2 * tid];
        c1 += rows[r * 2048 + 2 * tid + 1];
    }
    int s = c0 + c1;
    int E = excl_scan1024(s, tid, wsum);
    const int RK[4] = {13107, 13108, 249035, 249036};
#pragma unroll
    for (int t = 0; t < 4; t++) {
        int r = RK[t];
        if (r >= E && r < E + s) {
            if (r < E + c0) { binT[t] = 2 * tid;     remT[t] = r - E; }
            else            { binT[t] = 2 * tid + 1; remT[t] = r - E - c0; }
        }
    }
    __syncthreads();
    if (tid == 0) {
        for (int t = 0; t < 4; t++) { ctrl[ST_OFF + t] = binT[t]; ctrl[ST_OFF + 4 + t] = remT[t]; }
        for (int t = 0; t < 4; t++) {
            int g = t;
            for (int q = 0; q < t; q++) if (binT[q] == binT[t]) { g = q; break; }
            ctrl[ST_OFF + 8 + t] = g;
        }
    }
}

__global__ __launch_bounds__(W_THR) void hist2_kernel(const float* __restrict__ xf,
                                                      int* __restrict__ ctrl)
{
    const int tid = threadIdx.x, bl = blockIdx.x;
    int pf[4], gp[4];
#pragma unroll
    for (int t = 0; t < 4; t++) { pf[t] = ctrl[ST_OFF + t]; gp[t] = ctrl[ST_OFF + 8 + t]; }
    float4 v = ((const float4*)xf)[(size_t)bl * W_THR + tid];
    float xv[4] = {v.x, v.y, v.z, v.w};
#pragma unroll
    for (int k = 0; k < 4; k++) {
        unsigned u = fkey(xv[k]);
        unsigned hi = u >> 21;
        int bin = (int)((u >> 10) & 2047u);
        int code = -1;
#pragma unroll
        for (int t = 0; t < 4; t++)
            if (gp[t] == t && (unsigned)pf[t] == hi) code = t * 2048 + bin;
        aggAdd(ctrl + H2_OFF, code);
    }
}

__global__ __launch_bounds__(1024) void scan2_kernel(int* __restrict__ ctrl)
{
    __shared__ int wsum[16];
    __shared__ int binT[4], remT[4];
    const int tid = threadIdx.x;
    for (int t = 0; t < 4; t++) {
        int g = ctrl[ST_OFF + 8 + t], rank = ctrl[ST_OFF + 4 + t];
        const int* h = ctrl + H2_OFF + g * 2048;
        int c0 = h[2 * tid], c1 = h[2 * tid + 1];
        int s = c0 + c1;
        int E = excl_scan1024(s, tid, wsum);
        if (rank >= E && rank < E + s) {
            if (rank < E + c0) { binT[t] = 2 * tid;     remT[t] = rank - E; }
            else               { binT[t] = 2 * tid + 1; remT[t] = rank - E - c0; }
        }
        __syncthreads();
    }
    if (tid == 0) {
        int P2n[4];
        for (int t = 0; t < 4; t++) {
            P2n[t] = (ctrl[ST_OFF + t] << 11) | binT[t];
            ctrl[ST_OFF + 12 + t] = P2n[t];
            ctrl[ST_OFF + 16 + t] = remT[t];
        }
        for (int t = 0; t < 4; t++) {
            int g = t;
            for (int q = 0; q < t; q++) if (P2n[q] == P2n[t]) { g = q; break; }
            ctrl[ST_OFF + 20 + t] = g;
        }
    }
}

__global__ __launch_bounds__(W_THR) void hist3_kernel(const float* __restrict__ xf,
                                                      int* __restrict__ ctrl)
{
    const int tid = threadIdx.x, bl = blockIdx.x;
    int pf[4], gp[4];
#pragma unroll
    for (int t = 0; t < 4; t++) { pf[t] = ctrl[ST_OFF + 12 + t]; gp[t] = ctrl[ST_OFF + 20 + t]; }
    float4 v = ((const float4*)xf)[(size_t)bl * W_THR + tid];
    float xv[4] = {v.x, v.y, v.z, v.w};
#pragma unroll
    for (int k = 0; k < 4; k++) {
        unsigned u = fkey(xv[k]);
        unsigned hi = u >> 10;
        int bin = (int)(u & 1023u);
        int code = -1;
#pragma unroll
        for (int t = 0; t < 4; t++)
            if (gp[t] == t && (unsigned)pf[t] == hi) code = t * 1024 + bin;
        aggAdd(ctrl + H3_OFF, code);
    }
}

__global__ __launch_bounds__(1024) void scan3_kernel(int* __restrict__ ctrl)
{
    __shared__ int wsum[16];
    __shared__ int binT[4];
    const int tid = threadIdx.x;
    for (int t = 0; t < 4; t++) {
        int g = ctrl[ST_OFF + 20 + t], rank = ctrl[ST_OFF + 16 + t];
        const int* h = ctrl + H3_OFF + g * 1024;
        int s = h[tid];
        int E = excl_scan1024(s, tid, wsum);
        if (rank >= E && rank < E + s) binT[t] = tid;
        __syncthreads();
    }
    if (tid == 0) {
        float* sf = (float*)(ctrl + SF_OFF);
        float v[4];
        for (int t = 0; t < 4; t++) {
            unsigned key = ((unsigned)ctrl[ST_OFF + 12 + t] << 10) | (unsigned)binT[t];
            v[t] = funkey(key);
            sf[t] = v[t];
        }
        sf[4] = v[0] + 0.15f * (v[1] - v[0]);  // p5  (idx 0.05*(B-1)=13107.15)
        sf[5] = v[2] + 0.85f * (v[3] - v[2]);  // p95 (idx 0.95*(B-1)=249035.85)
    }
}

__global__ __launch_bounds__(W_THR) void tail_kernel(const float* __restrict__ xf,
                                                     const int* __restrict__ ctrl,
                                                     float* __restrict__ ws)
{
    __shared__ float frd[4][4];
    const int tid = threadIdx.x, bl = blockIdx.x;
    const float* sf = (const float*)(ctrl + SF_OFF);
    const float p5 = sf[4], p95 = sf[5];
    float4 v = ((const float4*)xf)[(size_t)bl * W_THR + tid];
    float xv[4] = {v.x, v.y, v.z, v.w};
    float slo = 0.f, clo = 0.f, shi = 0.f, chi = 0.f;
#pragma unroll
    for (int k = 0; k < 4; k++) {
        float x = xv[k];
        if (x < p5)  { slo += x; clo += 1.f; }
        if (x > p95) { shi += x; chi += 1.f; }
    }
    slo = wred(slo); clo = wred(clo); shi = wred(shi); chi = wred(chi);
    int wid = tid >> 6, lane = tid & 63;
    if (lane == 0) { frd[wid][0] = slo; frd[wid][1] = clo; frd[wid][2] = shi; frd[wid][3] = chi; }
    __syncthreads();
    if (tid == 0) {
        float s0 = 0, s1 = 0, s2 = 0, s3 = 0;
#pragma unroll
        for (int w = 0; w < 4; w++) { s0 += frd[w][0]; s1 += frd[w][1]; s2 += frd[w][2]; s3 += frd[w][3]; }
        float* tp = ws + TAILP_OFF + bl * 4;
        tp[0] = s0; tp[1] = s1; tp[2] = s2; tp[3] = s3;
    }
}

__global__ __launch_bounds__(256) void tailfin_kernel(const float* __restrict__ ws,
                                                      float* __restrict__ out)
{
    __shared__ float frd[4][4];
    const int tid = threadIdx.x;
    const float* tp = ws + TAILP_OFF;
    float a0 = tp[tid * 4 + 0], a1 = tp[tid * 4 + 1], a2 = tp[tid * 4 + 2], a3 = tp[tid * 4 + 3];
    a0 = wred(a0); a1 = wred(a1); a2 = wred(a2); a3 = wred(a3);
    int wid = tid >> 6, lane = tid & 63;
    if (lane == 0) { frd[wid][0] = a0; frd[wid][1] = a1; frd[wid][2] = a2; frd[wid][3] = a3; }
    __syncthreads();
    if (tid == 0) {
        float Slo = 0, Clo = 0, Shi = 0, Chi = 0;
#pragma unroll
        for (int w = 0; w < 4; w++) { Slo += frd[w][0]; Clo += frd[w][1]; Shi += frd[w][2]; Chi += frd[w][3]; }
        out[2] = -Slo / fmaxf(Clo, 1.f);
        out[3] = -Shi / fmaxf(Chi, 1.f);
    }
}

// ---------------- host ----------------
extern "C" void kernel_launch(void* const* d_in, const int* in_sizes, int n_in,
                              void* d_out, int out_size, void* d_ws, size_t ws_size,
                              hipStream_t stream)
{
    const float* x_in = (const float*)d_in[0];
    const float* dW   = (const float*)d_in[1];
    const float* Wo   = (const float*)d_in[2];
    const float* bo   = (const float*)d_in[3];
    const float* Wk   = (const float*)d_in[4];
    const float* bk   = (const float*)d_in[5];
    const float* Wu0  = (const float*)d_in[6];
    const float* bu0  = (const float*)d_in[7];
    const float* W1   = (const float*)d_in[8];
    const float* b1   = (const float*)d_in[9];
    const float* W2   = (const float*)d_in[10];
    const float* b2   = (const float*)d_in[11];
    const float* W3   = (const float*)d_in[12];
    const float* b3   = (const float*)d_in[13];
    float* ws   = (float*)d_ws;
    int* ctrl   = (int*)d_ws + ICTRL;
    float* prep = ws + PREP_OFF;
    float* out  = (float*)d_out;

    zero_kernel<<<(ZTOT + 1023) / 1024, 1024, 0, stream>>>(ctrl);
    prep_kernel<<<20, 256, 0, stream>>>(Wu0, bu0, W1, b1, W2, b2, W3, b3, prep);
    sim_kernel<<<NBLK_SIM, THB_SIM, 0, stream>>>(x_in, dW, Wo, bo, Wk, bk, ws, ctrl, out, prep);
    hist1_kernel<<<H1_BLK, H1_THR, 0, stream>>>(ws, ctrl);
    scan1_kernel<<<1, 1024, 0, stream>>>(ctrl);
    hist2_kernel<<<W_BLK, W_THR, 0, stream>>>(ws, ctrl);
    scan2_kernel<<<1, 1024, 0, stream>>>(ctrl);
    hist3_kernel<<<W_BLK, W_THR, 0, stream>>>(ws, ctrl);
    scan3_kernel<<<1, 1024, 0, stream>>>(ctrl);
    tail_kernel<<<W_BLK, W_THR, 0, stream>>>(ws, ctrl, ws);
    tailfin_kernel<<<1, 256, 0, stream>>>(ws, out);
}